// Round 12
// 1059.401 us; speedup vs baseline: 2.9438x; 1.0053x over previous
//
#include <hip/hip_runtime.h>

#define BN_EPS 1e-5f
#define MFMA_B16(a, b, c) __builtin_amdgcn_mfma_f32_16x16x32_bf16((a), (b), (c), 0, 0, 0)

typedef short s16x8 __attribute__((ext_vector_type(8)));
typedef float f32x4v __attribute__((ext_vector_type(4)));

__device__ __forceinline__ unsigned fenc(float f) {
    unsigned u = __float_as_uint(f);
    return (u & 0x80000000u) ? ~u : (u | 0x80000000u);
}
__device__ __forceinline__ float fdec(unsigned e) {
    unsigned u = (e & 0x80000000u) ? (e ^ 0x80000000u) : ~e;
    return __uint_as_float(u);
}
__device__ __forceinline__ unsigned short f2b(float f) {
    unsigned u = __float_as_uint(f);
    unsigned r = u + 0x7FFFu + ((u >> 16) & 1u);
    return (unsigned short)(r >> 16);
}
__device__ __forceinline__ float b2f(unsigned short h) {
    return __uint_as_float(((unsigned)h) << 16);
}

// ---------- build concatenated xyz (B,1280,3) ----------
__global__ __launch_bounds__(256) void build_xyz_kernel(
    const float* __restrict__ pc, const float* __restrict__ gpc, float* __restrict__ xyz)
{
    int p = blockIdx.x * 256 + threadIdx.x;
    if (p >= 64 * 1280) return;
    int b = p / 1280, i = p % 1280;
    const float* src = (i < 1024) ? (pc + ((size_t)b * 1024 + i) * 3)
                                  : (gpc + ((size_t)b * 256 + (i - 1024)) * 3);
    xyz[(size_t)p * 3 + 0] = src[0];
    xyz[(size_t)p * 3 + 1] = src[1];
    xyz[(size_t)p * 3 + 2] = src[2];
}

// ---------- prep: transpose SA1+SA2 weights to split-bf16 W^T[n][k] (hi+lo) ----------
__global__ __launch_bounds__(256) void prep_w_kernel(
    const float* __restrict__ w2a, const float* __restrict__ w2b, const float* __restrict__ w2c,
    const float* __restrict__ w1a, const float* __restrict__ w1b, const float* __restrict__ w1c,
    unsigned short* __restrict__ W1Th, unsigned short* __restrict__ W1Tl,
    unsigned short* __restrict__ W2Th, unsigned short* __restrict__ W2Tl,
    unsigned short* __restrict__ W3Th, unsigned short* __restrict__ W3Tl,
    unsigned short* __restrict__ A1Th, unsigned short* __restrict__ A1Tl,
    unsigned short* __restrict__ B1Th, unsigned short* __restrict__ B1Tl,
    unsigned short* __restrict__ C1Th, unsigned short* __restrict__ C1Tl)
{
    int i = blockIdx.x * 256 + threadIdx.x;
    float v = 0.f;
    unsigned short* dh; unsigned short* dl; int j;
    if (i < 20480) {                       // SA2 W1T 128 x 160
        int n = i / 160, k = i % 160;
        if (k < 128)       v = w2a[(size_t)(3 + k) * 128 + n];
        else if (k < 131)  v = w2a[(size_t)(k - 128) * 128 + n];
        dh = W1Th; dl = W1Tl; j = i;
    } else if (i < 36864) {                // SA2 W2T 128 x 128
        j = i - 20480;
        int n = j / 128, k = j % 128;
        v = w2b[(size_t)k * 128 + n];
        dh = W2Th; dl = W2Tl;
    } else if (i < 69632) {                // SA2 W3T 256 x 128
        j = i - 36864;
        int n = j / 128, k = j % 128;
        v = w2c[(size_t)k * 256 + n];
        dh = W3Th; dl = W3Tl;
    } else if (i < 71680) {                // SA1 A1T 64 x 32
        j = i - 69632;
        int n = j / 32, k = j % 32;
        if (k < 7) v = w1a[(size_t)k * 64 + n];
        dh = A1Th; dl = A1Tl;
    } else if (i < 75776) {                // SA1 B1T 64 x 64
        j = i - 71680;
        int n = j / 64, k = j % 64;
        v = w1b[(size_t)k * 64 + n];
        dh = B1Th; dl = B1Tl;
    } else if (i < 83968) {                // SA1 C1T 128 x 64
        j = i - 75776;
        int n = j / 64, k = j % 64;
        v = w1c[(size_t)k * 128 + n];
        dh = C1Th; dl = C1Tl;
    } else return;
    unsigned short hi = f2b(v);
    unsigned short lo = f2b(v - b2f(hi));
    dh[j] = hi; dl[j] = lo;
}

// ---------- reduce per-block stat partials ----------
__global__ __launch_bounds__(256) void reduce_stats_kernel(
    const float* __restrict__ PS, const float* __restrict__ PQ,
    int nblk, int C, float* __restrict__ osum, float* __restrict__ osq)
{
    __shared__ float rs_[256], rq_[256];
    int c = blockIdx.x, t = threadIdx.x;
    float s = 0.f, q = 0.f;
    for (int i = t; i < nblk; i += 256) {
        s += PS[(size_t)i * C + c];
        q += PQ[(size_t)i * C + c];
    }
    rs_[t] = s; rq_[t] = q;
    __syncthreads();
    for (int off = 128; off >= 1; off >>= 1) {
        if (t < off) { rs_[t] += rs_[t + off]; rq_[t] += rq_[t + off]; }
        __syncthreads();
    }
    if (t == 0) { osum[c] = rs_[0]; osq[c] = rq_[0]; }
}

// ---------- FPS: one wave per batch, register-resident distances ----------
template<int P>
__global__ __launch_bounds__(64) void fps_wave_kernel(
    const float* __restrict__ xyz, int N, int S, int* __restrict__ oidx)
{
    __shared__ float sx[1280 * 3];
    int b = blockIdx.x, lane = threadIdx.x;
    for (int i = lane; i < N * 3; i += 64) sx[i] = xyz[(size_t)b * N * 3 + i];
    __syncthreads();
    float px[P], py[P], pz[P], dm[P];
    #pragma unroll
    for (int p = 0; p < P; p++) {
        int i = lane * P + p;
        px[p] = sx[i * 3]; py[p] = sx[i * 3 + 1]; pz[p] = sx[i * 3 + 2];
        dm[p] = 1e10f;
    }
    int last = 0;
    for (int j = 0; j < S; j++) {
        if (lane == 0) oidx[b * S + j] = last;
        float lx = sx[last * 3], ly = sx[last * 3 + 1], lz = sx[last * 3 + 2];
        float bestv = -1.f; int besti = 0;
        #pragma unroll
        for (int p = 0; p < P; p++) {
            float dx = px[p] - lx, dy = py[p] - ly, dz = pz[p] - lz;
            float d2 = __fadd_rn(__fadd_rn(__fmul_rn(dx, dx), __fmul_rn(dy, dy)), __fmul_rn(dz, dz));
            float d = fminf(dm[p], d2); dm[p] = d;
            if (d > bestv) { bestv = d; besti = lane * P + p; }
        }
        #pragma unroll
        for (int off = 32; off > 0; off >>= 1) {
            float ov = __shfl_xor(bestv, off, 64);
            int   oi = __shfl_xor(besti, off, 64);
            if (ov > bestv || (ov == bestv && oi < besti)) { bestv = ov; besti = oi; }
        }
        last = besti;
    }
}

// ---------- ball query ----------
__global__ __launch_bounds__(256) void ball_query_kernel(
    const float* __restrict__ xyz, const int* __restrict__ cidx,
    int N, int S, int nsample, float r2,
    int* __restrict__ nidx, float* __restrict__ newxyz)
{
    __shared__ float sx[1280 * 3];
    int b = blockIdx.x, t = threadIdx.x;
    for (int i = t; i < N * 3; i += 256) sx[i] = xyz[(size_t)b * N * 3 + i];
    __syncthreads();
    int w = t >> 6, lane = t & 63;
    int s = blockIdx.y * 4 + w;
    if (s >= S) return;
    int c = cidx[b * S + s];
    float cx = sx[c * 3], cy = sx[c * 3 + 1], cz = sx[c * 3 + 2];
    if (lane == 0) {
        newxyz[((size_t)b * S + s) * 3 + 0] = cx;
        newxyz[((size_t)b * S + s) * 3 + 1] = cy;
        newxyz[((size_t)b * S + s) * 3 + 2] = cz;
    }
    int P = N >> 6;
    int base = lane * P;
    unsigned mask = 0;
    for (int p = 0; p < P; p++) {
        int i = base + p;
        float dx = sx[i * 3] - cx, dy = sx[i * 3 + 1] - cy, dz = sx[i * 3 + 2] - cz;
        float d2 = __fadd_rn(__fadd_rn(__fmul_rn(dx, dx), __fmul_rn(dy, dy)), __fmul_rn(dz, dz));
        if (d2 < r2) mask |= (1u << p);
    }
    int cnt = __popc(mask);
    int pre = cnt;
    for (int off = 1; off < 64; off <<= 1) {
        int v = __shfl_up(pre, off, 64);
        if (lane >= off) pre += v;
    }
    int excl = pre - cnt;
    int total = __shfl(pre, 63, 64);
    size_t outb = ((size_t)b * S + s) * (size_t)nsample;
    unsigned mm = mask; int pos = excl;
    while (mm) {
        int p = __ffs(mm) - 1; mm &= mm - 1;
        if (pos < nsample) nidx[outb + pos] = base + p;
        pos++;
    }
    unsigned long long bal = __ballot(cnt > 0);
    int firstlane = __ffsll(bal) - 1;
    int firstidx = base + __ffs(mask) - 1;
    firstidx = __shfl(firstidx, firstlane, 64);
    for (int p = total + lane; p < nsample; p += 64) nidx[outb + p] = firstidx;
}

// =====================================================================
// SA kernels.
// =====================================================================

// ---- SA1 S: gather X, layer a (K=32), STATS ONLY (no Y write) ----
__global__ __launch_bounds__(256) void sa1_s_kernel(
    const float* __restrict__ xyz, const int* __restrict__ nidx,
    const float* __restrict__ nx,
    const unsigned short* __restrict__ Wh, const unsigned short* __restrict__ Wl,
    float* __restrict__ ps, float* __restrict__ pq)
{
    __shared__ unsigned short Xhi[64 * 40], Xlo[64 * 40];
    __shared__ float cs[64], cq[64];
    int bs = blockIdx.x, b = bs >> 7, t = threadIdx.x;
    if (t < 64) {
        cs[t] = 0.f; cq[t] = 0.f;
        int n = nidx[(size_t)bs * 64 + t];
        const float* p = xyz + ((size_t)b * 1280 + n) * 3;
        float cx = nx[bs * 3], cy = nx[bs * 3 + 1], cz = nx[bs * 3 + 2];
        float v[7] = { p[0] - cx, p[1] - cy, p[2] - cz, p[0], p[1], p[2], (n < 1024) ? 1.f : 0.f };
        #pragma unroll
        for (int k = 0; k < 7; k++) {
            unsigned short hi = f2b(v[k]);
            Xhi[t * 40 + k] = hi;
            Xlo[t * 40 + k] = f2b(v[k] - b2f(hi));
        }
        for (int k = 7; k < 40; k++) { Xhi[t * 40 + k] = 0; Xlo[t * 40 + k] = 0; }
    }
    __syncthreads();
    int wv = t >> 6, lane = t & 63;
    int quad = lane >> 4, l16 = lane & 15;
    int aoff = quad * 8;

    f32x4v acc[4] = {};
    {
        size_t woff = (size_t)(wv * 16 + l16) * 32 + aoff;
        s16x8 bh = *(const s16x8*)(Wh + woff);
        s16x8 bl = *(const s16x8*)(Wl + woff);
        #pragma unroll
        for (int mt = 0; mt < 4; mt++) {
            s16x8 ah = *(const s16x8*)&Xhi[(mt * 16 + l16) * 40 + aoff];
            s16x8 al = *(const s16x8*)&Xlo[(mt * 16 + l16) * 40 + aoff];
            acc[mt] = MFMA_B16(al, bh, acc[mt]);
            acc[mt] = MFMA_B16(ah, bl, acc[mt]);
            acc[mt] = MFMA_B16(ah, bh, acc[mt]);
        }
    }
    int n = wv * 16 + l16;
    float s = 0.f, q = 0.f;
    #pragma unroll
    for (int mt = 0; mt < 4; mt++)
        #pragma unroll
        for (int r = 0; r < 4; r++) { float v = acc[mt][r]; s += v; q += v * v; }
    atomicAdd(&cs[n], s); atomicAdd(&cq[n], q);
    __syncthreads();
    if (t < 64) { ps[(size_t)bs * 64 + t] = cs[t]; pq[(size_t)bs * 64 + t] = cq[t]; }
}

// ---- SA1 AB (fused): re-gather, layer a, BN-a, layer b (K=64), write Y(b raw) + stats ----
__global__ __launch_bounds__(256) void sa1_ab_kernel(
    const float* __restrict__ xyz, const int* __restrict__ nidx,
    const float* __restrict__ nx,
    const unsigned short* __restrict__ W1h, const unsigned short* __restrict__ W1l,
    const unsigned short* __restrict__ W2h, const unsigned short* __restrict__ W2l,
    const float* __restrict__ s1, const float* __restrict__ q1,
    const float* __restrict__ g1, const float* __restrict__ b1,
    float* __restrict__ ps, float* __restrict__ pq, float* __restrict__ Y)
{
    __shared__ unsigned short Xhi[64 * 40], Xlo[64 * 40];
    __shared__ unsigned short Hh[64 * 72], Hl[64 * 72];
    __shared__ float aA[64], aB[64];
    __shared__ float cs[64], cq[64];
    const float IR = 1.f / 524288.f;
    int bs = blockIdx.x, b = bs >> 7, t = threadIdx.x;
    if (t < 64) {
        cs[t] = 0.f; cq[t] = 0.f;
        float mu = s1[t] * IR;
        float rs = rsqrtf(q1[t] * IR - mu * mu + BN_EPS);
        float a = rs * g1[t];
        aA[t] = a; aB[t] = b1[t] - mu * a;
        int n = nidx[(size_t)bs * 64 + t];
        const float* p = xyz + ((size_t)b * 1280 + n) * 3;
        float cx = nx[bs * 3], cy = nx[bs * 3 + 1], cz = nx[bs * 3 + 2];
        float v[7] = { p[0] - cx, p[1] - cy, p[2] - cz, p[0], p[1], p[2], (n < 1024) ? 1.f : 0.f };
        #pragma unroll
        for (int k = 0; k < 7; k++) {
            unsigned short hi = f2b(v[k]);
            Xhi[t * 40 + k] = hi;
            Xlo[t * 40 + k] = f2b(v[k] - b2f(hi));
        }
        for (int k = 7; k < 40; k++) { Xhi[t * 40 + k] = 0; Xlo[t * 40 + k] = 0; }
    }
    __syncthreads();
    int wv = t >> 6, lane = t & 63;
    int quad = lane >> 4, l16 = lane & 15;
    int aoff = quad * 8;

    // layer a (12 MFMA)
    f32x4v acc[4] = {};
    {
        size_t woff = (size_t)(wv * 16 + l16) * 32 + aoff;
        s16x8 bh = *(const s16x8*)(W1h + woff);
        s16x8 bl = *(const s16x8*)(W1l + woff);
        #pragma unroll
        for (int mt = 0; mt < 4; mt++) {
            s16x8 ah = *(const s16x8*)&Xhi[(mt * 16 + l16) * 40 + aoff];
            s16x8 al = *(const s16x8*)&Xlo[(mt * 16 + l16) * 40 + aoff];
            acc[mt] = MFMA_B16(al, bh, acc[mt]);
            acc[mt] = MFMA_B16(ah, bl, acc[mt]);
            acc[mt] = MFMA_B16(ah, bh, acc[mt]);
        }
    }
    // BN-a + ReLU -> Hh/Hl (split bf16)
    {
        int n = wv * 16 + l16;
        float a = aA[n], bb = aB[n];
        #pragma unroll
        for (int mt = 0; mt < 4; mt++)
            #pragma unroll
            for (int r = 0; r < 4; r++) {
                int m = mt * 16 + quad * 4 + r;
                float h = fmaxf(acc[mt][r] * a + bb, 0.f);
                unsigned short hi = f2b(h);
                Hh[m * 72 + n] = hi;
                Hl[m * 72 + n] = f2b(h - b2f(hi));
            }
    }
    __syncthreads();

    // layer b (24 MFMA), write Y + stats
    f32x4v ac2[4] = {};
    for (int kc = 0; kc < 64; kc += 32) {
        size_t woff = (size_t)(wv * 16 + l16) * 64 + kc + aoff;
        s16x8 bh = *(const s16x8*)(W2h + woff);
        s16x8 bl = *(const s16x8*)(W2l + woff);
        #pragma unroll
        for (int mt = 0; mt < 4; mt++) {
            s16x8 ah = *(const s16x8*)&Hh[(mt * 16 + l16) * 72 + kc + aoff];
            s16x8 al = *(const s16x8*)&Hl[(mt * 16 + l16) * 72 + kc + aoff];
            ac2[mt] = MFMA_B16(al, bh, ac2[mt]);
            ac2[mt] = MFMA_B16(ah, bl, ac2[mt]);
            ac2[mt] = MFMA_B16(ah, bh, ac2[mt]);
        }
    }
    int n = wv * 16 + l16;
    float s = 0.f, q = 0.f;
    #pragma unroll
    for (int mt = 0; mt < 4; mt++)
        #pragma unroll
        for (int r = 0; r < 4; r++) {
            int m = mt * 16 + quad * 4 + r;
            float v = ac2[mt][r];
            Y[((size_t)bs * 64 + m) * 64 + n] = v;
            s += v; q += v * v;
        }
    atomicAdd(&cs[n], s); atomicAdd(&cq[n], q);
    __syncthreads();
    if (t < 64) { ps[(size_t)bs * 64 + t] = cs[t]; pq[(size_t)bs * 64 + t] = cq[t]; }
}

// ---- SA1 C: 2 groups/block, BN-b + layer c (128x128, K=64), stats + per-group pool ----
__global__ __launch_bounds__(256) void sa1_c_kernel(
    const float* __restrict__ Y,
    const unsigned short* __restrict__ Wh, const unsigned short* __restrict__ Wl,
    const float* __restrict__ s2, const float* __restrict__ q2,
    const float* __restrict__ g2, const float* __restrict__ b2,
    float* __restrict__ ps, float* __restrict__ pq,
    float* __restrict__ pmax, float* __restrict__ pmin)
{
    __shared__ unsigned short Xhi[128 * 72], Xlo[128 * 72];
    __shared__ float aA[64], aB[64];
    __shared__ float cs[128], cq[128];
    __shared__ unsigned cmx[2][128], cmn[2][128];
    const float IR = 1.f / 524288.f;
    int bs0 = blockIdx.x * 2;
    size_t rbase = (size_t)blockIdx.x * 128;
    int t = threadIdx.x;
    if (t < 128) {
        cs[t] = 0.f; cq[t] = 0.f;
        cmx[0][t] = 0u; cmx[1][t] = 0u;
        cmn[0][t] = 0xFFFFFFFFu; cmn[1][t] = 0xFFFFFFFFu;
    }
    if (t < 64) {
        float mu = s2[t] * IR;
        float rs = rsqrtf(q2[t] * IR - mu * mu + BN_EPS);
        float a = rs * g2[t];
        aA[t] = a; aB[t] = b2[t] - mu * a;
    }
    __syncthreads();
    {
        int r = t >> 1, seg = t & 1;
        const float4* y4 = (const float4*)(Y + (rbase + r) * 64 + seg * 32);
        float4 v[8];
        #pragma unroll
        for (int i = 0; i < 8; i++) v[i] = y4[i];
        #pragma unroll
        for (int i = 0; i < 8; i++) {
            #pragma unroll
            for (int j = 0; j < 4; j++) {
                int c = seg * 32 + i * 4 + j;
                float x = fmaxf(((const float*)&v[i])[j] * aA[c] + aB[c], 0.f);
                unsigned short hi = f2b(x);
                Xhi[r * 72 + c] = hi;
                Xlo[r * 72 + c] = f2b(x - b2f(hi));
            }
        }
    }
    __syncthreads();
    int wv = t >> 6, lane = t & 63;
    int quad = lane >> 4, l16 = lane & 15;
    int aoff = quad * 8;

    f32x4v a3[8][2] = {};
    for (int kc = 0; kc < 64; kc += 32) {
        #pragma unroll
        for (int nt = 0; nt < 2; nt++) {
            size_t woff = (size_t)(wv * 32 + nt * 16 + l16) * 64 + kc + aoff;
            s16x8 bh = *(const s16x8*)(Wh + woff);
            s16x8 bl = *(const s16x8*)(Wl + woff);
            #pragma unroll
            for (int mt = 0; mt < 8; mt++) {
                s16x8 ah = *(const s16x8*)&Xhi[(mt * 16 + l16) * 72 + kc + aoff];
                s16x8 al = *(const s16x8*)&Xlo[(mt * 16 + l16) * 72 + kc + aoff];
                a3[mt][nt] = MFMA_B16(al, bh, a3[mt][nt]);
                a3[mt][nt] = MFMA_B16(ah, bl, a3[mt][nt]);
                a3[mt][nt] = MFMA_B16(ah, bh, a3[mt][nt]);
            }
        }
    }
    #pragma unroll
    for (int nt = 0; nt < 2; nt++) {
        int n = wv * 32 + nt * 16 + l16;
        float s = 0.f, q = 0.f;
        #pragma unroll
        for (int g = 0; g < 2; g++) {
            float mx = -3.4e38f, mn_ = 3.4e38f;
            #pragma unroll
            for (int mi = 0; mi < 4; mi++) {
                int mt = g * 4 + mi;
                #pragma unroll
                for (int r = 0; r < 4; r++) {
                    float v = a3[mt][nt][r]; s += v; q += v * v;
                    mx = fmaxf(mx, v); mn_ = fminf(mn_, v);
                }
            }
            atomicMax(&cmx[g][n], fenc(mx)); atomicMin(&cmn[g][n], fenc(mn_));
        }
        atomicAdd(&cs[n], s); atomicAdd(&cq[n], q);
    }
    __syncthreads();
    if (t < 128) {
        ps[(size_t)blockIdx.x * 128 + t] = cs[t]; pq[(size_t)blockIdx.x * 128 + t] = cq[t];
        pmax[(size_t)(bs0 + 0) * 128 + t] = fdec(cmx[0][t]);
        pmin[(size_t)(bs0 + 0) * 128 + t] = fdec(cmn[0][t]);
        pmax[(size_t)(bs0 + 1) * 128 + t] = fdec(cmx[1][t]);
        pmin[(size_t)(bs0 + 1) * 128 + t] = fdec(cmn[1][t]);
    }
}

// ---------- finalize SA1 pool -> BN+ReLU feature map FE1 (4 MB) ----------
__global__ __launch_bounds__(256) void bnpool_fin_kernel(
    const float* __restrict__ pmax, const float* __restrict__ pmin,
    const float* __restrict__ sum, const float* __restrict__ sq,
    const float* __restrict__ g, const float* __restrict__ bb,
    float rcnt, float* __restrict__ out, int total, int dmask)
{
    int i = blockIdx.x * 256 + threadIdx.x;
    if (i >= total) return;
    int d = i & dmask;
    float mu = sum[d] * rcnt;
    float rs = rsqrtf(sq[d] * rcnt - mu * mu + BN_EPS);
    float gv = g[d];
    float v = (gv >= 0.f) ? pmax[i] : pmin[i];
    out[i] = fmaxf((v - mu) * rs * gv + bb[d], 0.f);
}

// ---- SA2 A: 64 rows/block, gather FE1 (pre-BN'd), layer a (K=160) ----
__global__ __launch_bounds__(256) void sa2_a_kernel(
    const float* __restrict__ xyz1, const int* __restrict__ nidx2,
    const float* __restrict__ nx2, const float* __restrict__ feat1,
    const unsigned short* __restrict__ Wh, const unsigned short* __restrict__ Wl,
    float* __restrict__ ps, float* __restrict__ pq, float* __restrict__ Y)
{
    __shared__ unsigned short Xhi[64 * 168], Xlo[64 * 168];
    __shared__ float cs[128], cq[128];
    __shared__ int sn[64];
    int row0 = blockIdx.x * 64;
    int bs = row0 >> 7, b = bs >> 5;
    int t = threadIdx.x;
    if (t < 128) { cs[t] = 0.f; cq[t] = 0.f; }
    if (t < 64) sn[t] = nidx2[(size_t)bs * 128 + (row0 & 127) + t];
    __syncthreads();
    {
        int r = t >> 2, seg = t & 3;
        int n = sn[r];
        size_t base = ((size_t)(b * 128 + n)) * 128 + seg * 32;
        const float4* fr = (const float4*)(feat1 + base);
        float4 v[8];
        #pragma unroll
        for (int i = 0; i < 8; i++) v[i] = fr[i];
        #pragma unroll
        for (int i = 0; i < 8; i++) {
            #pragma unroll
            for (int j = 0; j < 4; j++) {
                int c = seg * 32 + i * 4 + j;
                float x = ((const float*)&v[i])[j];
                unsigned short hi = f2b(x);
                Xhi[r * 168 + c] = hi;
                Xlo[r * 168 + c] = f2b(x - b2f(hi));
            }
        }
        if (seg == 0) {
            float c3x = nx2[bs * 3], c3y = nx2[bs * 3 + 1], c3z = nx2[bs * 3 + 2];
            const float* pz = xyz1 + ((size_t)b * 128 + n) * 3;
            float g3[3] = { pz[0] - c3x, pz[1] - c3y, pz[2] - c3z };
            #pragma unroll
            for (int i = 0; i < 3; i++) {
                unsigned short hi = f2b(g3[i]);
                Xhi[r * 168 + 128 + i] = hi;
                Xlo[r * 168 + 128 + i] = f2b(g3[i] - b2f(hi));
            }
            for (int k = 131; k < 168; k++) { Xhi[r * 168 + k] = 0; Xlo[r * 168 + k] = 0; }
        }
    }
    __syncthreads();
    int wv = t >> 6, lane = t & 63;
    int quad = lane >> 4, l16 = lane & 15;
    int aoff = quad * 8;

    f32x4v acc[4][2] = {};
    for (int kc = 0; kc < 160; kc += 32) {
        #pragma unroll
        for (int nt = 0; nt < 2; nt++) {
            size_t woff = (size_t)(wv * 32 + nt * 16 + l16) * 160 + kc + aoff;
            s16x8 bh = *(const s16x8*)(Wh + woff);
            s16x8 bl = *(const s16x8*)(Wl + woff);
            #pragma unroll
            for (int mt = 0; mt < 4; mt++) {
                s16x8 ah = *(const s16x8*)&Xhi[(mt * 16 + l16) * 168 + kc + aoff];
                s16x8 al = *(const s16x8*)&Xlo[(mt * 16 + l16) * 168 + kc + aoff];
                acc[mt][nt] = MFMA_B16(al, bh, acc[mt][nt]);
                acc[mt][nt] = MFMA_B16(ah, bl, acc[mt][nt]);
                acc[mt][nt] = MFMA_B16(ah, bh, acc[mt][nt]);
            }
        }
    }
    #pragma unroll
    for (int nt = 0; nt < 2; nt++) {
        int n = wv * 32 + nt * 16 + l16;
        float s = 0.f, q = 0.f;
        #pragma unroll
        for (int mt = 0; mt < 4; mt++)
            #pragma unroll
            for (int r = 0; r < 4; r++) {
                int m = mt * 16 + quad * 4 + r;
                float v = acc[mt][nt][r];
                Y[((size_t)row0 + m) * 128 + n] = v;
                s += v; q += v * v;
            }
        atomicAdd(&cs[n], s); atomicAdd(&cq[n], q);
    }
    __syncthreads();
    if (t < 128) { ps[(size_t)blockIdx.x * 128 + t] = cs[t]; pq[(size_t)blockIdx.x * 128 + t] = cq[t]; }
}

// ---- SA2 B: 64 rows/block, BN-a + layer b (K=128), Y in place ----
__global__ __launch_bounds__(256) void sa2_b_kernel(
    float* __restrict__ Y,
    const unsigned short* __restrict__ Wh, const unsigned short* __restrict__ Wl,
    const float* __restrict__ s1, const float* __restrict__ q1,
    const float* __restrict__ g1, const float* __restrict__ b1,
    float* __restrict__ ps, float* __restrict__ pq)
{
    __shared__ unsigned short Xhi[64 * 136], Xlo[64 * 136];
    __shared__ float aA[128], aB[128];
    __shared__ float cs[128], cq[128];
    const float IR = 1.f / 262144.f;
    int row0 = blockIdx.x * 64;
    int t = threadIdx.x;
    if (t < 128) {
        cs[t] = 0.f; cq[t] = 0.f;
        float mu = s1[t] * IR;
        float rs = rsqrtf(q1[t] * IR - mu * mu + BN_EPS);
        float a = rs * g1[t];
        aA[t] = a; aB[t] = b1[t] - mu * a;
    }
    __syncthreads();
    {
        int r = t >> 2, seg = t & 3;
        const float4* y4 = (const float4*)(Y + ((size_t)row0 + r) * 128 + seg * 32);
        float4 v[8];
        #pragma unroll
        for (int i = 0; i < 8; i++) v[i] = y4[i];
        #pragma unroll
        for (int i = 0; i < 8; i++) {
            #pragma unroll
            for (int j = 0; j < 4; j++) {
                int c = seg * 32 + i * 4 + j;
                float x = fmaxf(((const float*)&v[i])[j] * aA[c] + aB[c], 0.f);
                unsigned short hi = f2b(x);
                Xhi[r * 136 + c] = hi;
                Xlo[r * 136 + c] = f2b(x - b2f(hi));
            }
        }
    }
    __syncthreads();
    int wv = t >> 6, lane = t & 63;
    int quad = lane >> 4, l16 = lane & 15;
    int aoff = quad * 8;

    f32x4v ac2[4][2] = {};
    for (int kc = 0; kc < 128; kc += 32) {
        #pragma unroll
        for (int nt = 0; nt < 2; nt++) {
            size_t woff = (size_t)(wv * 32 + nt * 16 + l16) * 128 + kc + aoff;
            s16x8 bh = *(const s16x8*)(Wh + woff);
            s16x8 bl = *(const s16x8*)(Wl + woff);
            #pragma unroll
            for (int mt = 0; mt < 4; mt++) {
                s16x8 ah = *(const s16x8*)&Xhi[(mt * 16 + l16) * 136 + kc + aoff];
                s16x8 al = *(const s16x8*)&Xlo[(mt * 16 + l16) * 136 + kc + aoff];
                ac2[mt][nt] = MFMA_B16(al, bh, ac2[mt][nt]);
                ac2[mt][nt] = MFMA_B16(ah, bl, ac2[mt][nt]);
                ac2[mt][nt] = MFMA_B16(ah, bh, ac2[mt][nt]);
            }
        }
    }
    #pragma unroll
    for (int nt = 0; nt < 2; nt++) {
        int n = wv * 32 + nt * 16 + l16;
        float s = 0.f, q = 0.f;
        #pragma unroll
        for (int mt = 0; mt < 4; mt++)
            #pragma unroll
            for (int r = 0; r < 4; r++) {
                int m = mt * 16 + quad * 4 + r;
                float v = ac2[mt][nt][r];
                Y[((size_t)row0 + m) * 128 + n] = v;
                s += v; q += v * v;
            }
        atomicAdd(&cs[n], s); atomicAdd(&cq[n], q);
    }
    __syncthreads();
    if (t < 128) { ps[(size_t)blockIdx.x * 128 + t] = cs[t]; pq[(size_t)blockIdx.x * 128 + t] = cq[t]; }
}

// ---- SA2 C: 64 rows/block, BN-b + layer c (64x256, K=128), stats + pool atomics ----
__global__ __launch_bounds__(256) void sa2_c_kernel(
    const float* __restrict__ Y,
    const unsigned short* __restrict__ Wh, const unsigned short* __restrict__ Wl,
    const float* __restrict__ s2, const float* __restrict__ q2,
    const float* __restrict__ g2, const float* __restrict__ b2,
    float* __restrict__ ps, float* __restrict__ pq,
    unsigned* __restrict__ pmax, unsigned* __restrict__ pmin)
{
    __shared__ unsigned short Xhi[64 * 136], Xlo[64 * 136];
    __shared__ float aA[128], aB[128];
    __shared__ float cs[256], cq[256];
    __shared__ unsigned cmx[256], cmn[256];
    const float IR = 1.f / 262144.f;
    int row0 = blockIdx.x * 64;
    int bs = row0 >> 7;
    int t = threadIdx.x;
    cs[t] = 0.f; cq[t] = 0.f; cmx[t] = 0u; cmn[t] = 0xFFFFFFFFu;
    if (t < 128) {
        float mu = s2[t] * IR;
        float rs = rsqrtf(q2[t] * IR - mu * mu + BN_EPS);
        float a = rs * g2[t];
        aA[t] = a; aB[t] = b2[t] - mu * a;
    }
    __syncthreads();
    {
        int r = t >> 2, seg = t & 3;
        const float4* y4 = (const float4*)(Y + ((size_t)row0 + r) * 128 + seg * 32);
        float4 v[8];
        #pragma unroll
        for (int i = 0; i < 8; i++) v[i] = y4[i];
        #pragma unroll
        for (int i = 0; i < 8; i++) {
            #pragma unroll
            for (int j = 0; j < 4; j++) {
                int c = seg * 32 + i * 4 + j;
                float x = fmaxf(((const float*)&v[i])[j] * aA[c] + aB[c], 0.f);
                unsigned short hi = f2b(x);
                Xhi[r * 136 + c] = hi;
                Xlo[r * 136 + c] = f2b(x - b2f(hi));
            }
        }
    }
    __syncthreads();
    int wv = t >> 6, lane = t & 63;
    int quad = lane >> 4, l16 = lane & 15;
    int aoff = quad * 8;

    f32x4v a3[4][4] = {};
    for (int kc = 0; kc < 128; kc += 32) {
        #pragma unroll
        for (int ct = 0; ct < 4; ct++) {
            size_t woff = (size_t)(wv * 64 + ct * 16 + l16) * 128 + kc + aoff;
            s16x8 bh = *(const s16x8*)(Wh + woff);
            s16x8 bl = *(const s16x8*)(Wl + woff);
            #pragma unroll
            for (int mt = 0; mt < 4; mt++) {
                s16x8 ah = *(const s16x8*)&Xhi[(mt * 16 + l16) * 136 + kc + aoff];
                s16x8 al = *(const s16x8*)&Xlo[(mt * 16 + l16) * 136 + kc + aoff];
                a3[mt][ct] = MFMA_B16(al, bh, a3[mt][ct]);
                a3[mt][ct] = MFMA_B16(ah, bl, a3[mt][ct]);
                a3[mt][ct] = MFMA_B16(ah, bh, a3[mt][ct]);
            }
        }
    }
    #pragma unroll
    for (int ct = 0; ct < 4; ct++) {
        int n = wv * 64 + ct * 16 + l16;
        float s = 0.f, q = 0.f, mx = -3.4e38f, mn = 3.4e38f;
        #pragma unroll
        for (int mt = 0; mt < 4; mt++)
            #pragma unroll
            for (int r = 0; r < 4; r++) {
                float v = a3[mt][ct][r]; s += v; q += v * v;
                mx = fmaxf(mx, v); mn = fminf(mn, v);
            }
        atomicAdd(&cs[n], s); atomicAdd(&cq[n], q);
        atomicMax(&cmx[n], fenc(mx)); atomicMin(&cmn[n], fenc(mn));
    }
    __syncthreads();
    ps[(size_t)blockIdx.x * 256 + t] = cs[t]; pq[(size_t)blockIdx.x * 256 + t] = cq[t];
    atomicMax(&pmax[(size_t)bs * 256 + t], cmx[t]);
    atomicMin(&pmin[(size_t)bs * 256 + t], cmn[t]);
}

// ---------- build SA3 input (2048 x 259) ----------
__global__ __launch_bounds__(256) void grouped3_prep_kernel(
    const float* __restrict__ nx2, const unsigned* __restrict__ pmax,
    const unsigned* __restrict__ pmin, const float* __restrict__ sum,
    const float* __restrict__ sq, const float* __restrict__ g,
    const float* __restrict__ bb, float rcnt, float* __restrict__ out)
{
    int row = blockIdx.x;
    int t = threadIdx.x;
    for (int c = t; c < 259; c += 256) {
        float v;
        if (c < 3) v = nx2[row * 3 + c];
        else {
            int d = c - 3;
            float mu = sum[d] * rcnt;
            float rs = rsqrtf(sq[d] * rcnt - mu * mu + BN_EPS);
            float gv = g[d];
            float x = fdec((gv >= 0.f) ? pmax[(size_t)row * 256 + d] : pmin[(size_t)row * 256 + d]);
            v = fmaxf((x - mu) * rs * gv + bb[d], 0.f);
        }
        out[(size_t)row * 259 + c] = v;
    }
}

// ---------- generic GEMM (SA3) ----------
__global__ __launch_bounds__(256) void gemm_bn_kernel(
    const float* __restrict__ X, const float* __restrict__ W,
    const float* __restrict__ bias, float* __restrict__ Y,
    const float* __restrict__ isum, const float* __restrict__ isq,
    const float* __restrict__ ig, const float* __restrict__ ib, float ircnt,
    float* __restrict__ osum, float* __restrict__ osq,
    int M, int C, int D)
{
    __shared__ float Xs[64 * 33];
    __shared__ float Ws[32 * 64];
    __shared__ float cs[64], cq[64];
    int m0 = blockIdx.x * 64;
    int d0 = blockIdx.y * 64;
    int t = threadIdx.x;
    int tr = t >> 4, tc = t & 15, r0 = tr * 4, c0 = tc * 4;
    float acc[4][4] = {};
    int nchunk = (C + 31) / 32;
    for (int ch = 0; ch < nchunk; ch++) {
        int kbase = ch * 32;
        for (int f = t; f < 64 * 32; f += 256) {
            int r = f >> 5, c = f & 31; int gc = kbase + c;
            float v = 0.f;
            if (gc < C) {
                v = X[(size_t)(m0 + r) * C + gc];
                if (isum) {
                    float mu = isum[gc] * ircnt;
                    float rs = rsqrtf(isq[gc] * ircnt - mu * mu + BN_EPS);
                    v = fmaxf((v - mu) * rs * ig[gc] + ib[gc], 0.f);
                }
            }
            Xs[r * 33 + c] = v;
        }
        for (int f = t; f < 32 * 64; f += 256) {
            int c = f >> 6, j = f & 63; int gc = kbase + c;
            Ws[f] = (gc < C) ? W[(size_t)gc * D + d0 + j] : 0.f;
        }
        __syncthreads();
        #pragma unroll 8
        for (int kk = 0; kk < 32; kk++) {
            float xv[4], wv[4];
            #pragma unroll
            for (int i = 0; i < 4; i++) xv[i] = Xs[(r0 + i) * 33 + kk];
            #pragma unroll
            for (int j = 0; j < 4; j++) wv[j] = Ws[kk * 64 + c0 + j];
            #pragma unroll
            for (int i = 0; i < 4; i++)
                #pragma unroll
                for (int j = 0; j < 4; j++)
                    acc[i][j] = fmaf(xv[i], wv[j], acc[i][j]);
        }
        __syncthreads();
    }
    if (bias) {
        #pragma unroll
        for (int j = 0; j < 4; j++) {
            float bv = bias[d0 + c0 + j];
            #pragma unroll
            for (int i = 0; i < 4; i++) acc[i][j] += bv;
        }
    }
    #pragma unroll
    for (int i = 0; i < 4; i++) {
        float4 v = make_float4(acc[i][0], acc[i][1], acc[i][2], acc[i][3]);
        *(float4*)(Y + (size_t)(m0 + r0 + i) * D + d0 + c0) = v;
    }
    if (t < 64) { cs[t] = 0.f; cq[t] = 0.f; }
    __syncthreads();
    #pragma unroll
    for (int j = 0; j < 4; j++) {
        int col = c0 + j;
        float s = 0.f, q = 0.f;
        #pragma unroll
        for (int i = 0; i < 4; i++) { float v = acc[i][j]; s += v; q += v * v; }
        atomicAdd(&cs[col], s); atomicAdd(&cq[col], q);
    }
    __syncthreads();
    if (t < 64) { atomicAdd(&osum[d0 + t], cs[t]); atomicAdd(&osq[d0 + t], cq[t]); }
}

// ---------- FC split-K GEMM ----------
__global__ __launch_bounds__(256) void fc_gemm_kernel(
    const float* __restrict__ X, const float* __restrict__ W,
    const float* __restrict__ isum, const float* __restrict__ isq,
    const float* __restrict__ ig, const float* __restrict__ ib, float ircnt,
    float* __restrict__ PP, int C, int D)
{
    __shared__ float Xs[64 * 132];
    int d0 = blockIdx.x * 64;
    int KS = gridDim.y;
    int L = C / KS;
    int kbase = blockIdx.y * L;
    int t = threadIdx.x;
    for (int f = t; f < 64 * L; f += 256) {
        int r = f / L, k = f - r * L;
        int gc = kbase + k;
        float v = X[(size_t)r * C + gc];
        if (isum) {
            float mu = isum[gc] * ircnt;
            float rs = rsqrtf(isq[gc] * ircnt - mu * mu + BN_EPS);
            v = fmaxf((v - mu) * rs * ig[gc] + ib[gc], 0.f);
        }
        Xs[r * 132 + k] = v;
    }
    __syncthreads();
    int tr = t >> 4, tc = t & 15, r0 = tr * 4, c0 = tc * 4;
    float acc[4][4] = {};
    for (int k = 0; k < L; k++) {
        float xv[4];
        #pragma unroll
        for (int i = 0; i < 4; i++) xv[i] = Xs[(r0 + i) * 132 + k];
        float4 wv = *(const float4*)(W + (size_t)(kbase + k) * D + d0 + c0);
        #pragma unroll
        for (int i = 0; i < 4; i++) {
            acc[i][0] = fmaf(xv[i], wv.x, acc[i][0]);
            acc[i][1] = fmaf(xv[i], wv.y, acc[i][1]);
            acc[i][2] = fmaf(xv[i], wv.z, acc[i][2]);
            acc[i][3] = fmaf(xv[i], wv.w, acc[i][3]);
        }
    }
    float* pp = PP + (size_t)blockIdx.y * 64 * D;
    #pragma unroll
    for (int i = 0; i < 4; i++) {
        float4 v = make_float4(acc[i][0], acc[i][1], acc[i][2], acc[i][3]);
        *(float4*)(pp + (size_t)(r0 + i) * D + d0 + c0) = v;
    }
}

__global__ __launch_bounds__(256) void fc_fin_kernel(
    const float* __restrict__ PP, const float* __restrict__ bias,
    int D, int KS, float* __restrict__ Y)
{
    int i = blockIdx.x * 256 + threadIdx.x;
    if (i >= 64 * D) return;
    int n = i % D;
    float s = 0.f;
    for (int k = 0; k < KS; k++) s += PP[(size_t)k * 64 * D + i];
    Y[i] = s + bias[n];
}

__global__ __launch_bounds__(256) void col_stats_kernel(
    const float* __restrict__ Y, int M, int D,
    float* __restrict__ osum, float* __restrict__ osq)
{
    int c = blockIdx.x * 256 + threadIdx.x;
    if (c >= D) return;
    float s = 0.f, q = 0.f;
    for (int m = 0; m < M; m++) {
        float v = Y[(size_t)m * D + c];
        s += v; q += v * v;
    }
    osum[c] = s; osq[c] = q;
}

// ---------- SA3 pool ----------
__global__ __launch_bounds__(256) void pool3_kernel(
    const float* __restrict__ h, const float* __restrict__ sum,
    const float* __restrict__ sq, const float* __restrict__ g,
    const float* __restrict__ bb, float* __restrict__ out)
{
    int i = blockIdx.x * 256 + threadIdx.x;
    if (i >= 32768) return;
    int d = i & 511, b = i >> 9;
    const float rcnt = 1.f / 2048.f;
    float mu = sum[d] * rcnt;
    float rs = rsqrtf(sq[d] * rcnt - mu * mu + BN_EPS);
    float gv = g[d], bv = bb[d];
    float m = -3.4e38f;
    for (int k = 0; k < 32; k++) {
        float v = h[((size_t)b * 32 + k) * 512 + d];
        m = fmaxf(m, fmaxf((v - mu) * rs * gv + bv, 0.f));
    }
    out[i] = m;
}

// ---------- head ----------
__global__ __launch_bounds__(256) void head_kernel(
    const float* __restrict__ y2, const float* __restrict__ sum,
    const float* __restrict__ sq, const float* __restrict__ g,
    const float* __restrict__ bb, const float* __restrict__ hw,
    const float* __restrict__ hb, float* __restrict__ out)
{
    __shared__ float red[256];
    int b = blockIdx.x, t = threadIdx.x;
    const float rcnt = 1.f / 64.f;
    float part = 0.f;
    for (int d = t; d < 1024; d += 256) {
        float mu = sum[d] * rcnt;
        float rs = rsqrtf(sq[d] * rcnt - mu * mu + BN_EPS);
        float v = fmaxf((y2[(size_t)b * 1024 + d] - mu) * rs * g[d] + bb[d], 0.f);
        part = fmaf(v, hw[d], part);
    }
    red[t] = part; __syncthreads();
    if (t < 128) red[t] += red[t + 128];
    __syncthreads();
    if (t < 64) {
        float v = red[t] + red[t + 64];
        for (int off = 32; off > 0; off >>= 1) v += __shfl_down(v, off, 64);
        if (t == 0) out[b] = v + hb[0];
    }
}

extern "C" void kernel_launch(void* const* d_in, const int* in_sizes, int n_in,
                              void* d_out, int out_size, void* d_ws, size_t ws_size,
                              hipStream_t stream)
{
    (void)in_sizes; (void)n_in; (void)out_size; (void)ws_size;
    const float* pc  = (const float*)d_in[0];
    const float* gpc = (const float*)d_in[1];
    const float* w1a = (const float*)d_in[2];  const float* g1a = (const float*)d_in[3];  const float* b1a = (const float*)d_in[4];
    const float* w1b = (const float*)d_in[5];  const float* g1b = (const float*)d_in[6];  const float* b1b = (const float*)d_in[7];
    const float* w1c = (const float*)d_in[8];  const float* g1c = (const float*)d_in[9];  const float* b1c = (const float*)d_in[10];
    const float* w2a = (const float*)d_in[11]; const float* g2a = (const float*)d_in[12]; const float* b2a = (const float*)d_in[13];
    const float* w2b = (const float*)d_in[14]; const float* g2b = (const float*)d_in[15]; const float* b2b = (const float*)d_in[16];
    const float* w2c = (const float*)d_in[17]; const float* g2c = (const float*)d_in[18]; const float* b2c = (const float*)d_in[19];
    const float* w3a = (const float*)d_in[20]; const float* g3a = (const float*)d_in[21]; const float* b3a = (const float*)d_in[22];
    const float* w3b = (const float*)d_in[23]; const float* g3b = (const float*)d_in[24]; const float* b3b = (const float*)d_in[25];
    const float* w3c = (const float*)d_in[26]; const float* g3c = (const float*)d_in[27]; const float* b3c = (const float*)d_in[28];
    const float* fw1 = (const float*)d_in[29]; const float* fb1 = (const float*)d_in[30];
    const float* fg1 = (const float*)d_in[31]; const float* fbb1 = (const float*)d_in[32];
    const float* fw2 = (const float*)d_in[33]; const float* fb2 = (const float*)d_in[34];
    const float* fg2 = (const float*)d_in[35]; const float* fbb2 = (const float*)d_in[36];
    const float* hw  = (const float*)d_in[37]; const float* hb  = (const float*)d_in[38];
    float* out = (float*)d_out;

    char* ws = (char*)d_ws;
    size_t o = 0;
    auto take = [&](size_t nf) { size_t r = o; o += nf * 4; return r; };
    size_t XYZ  = take(245760);
    size_t CID1 = take(8192);
    size_t NID1 = take(524288);
    size_t NX1  = take(24576);
    size_t CID2 = take(2048);
    size_t NID2 = take(262144);
    size_t NX2  = take(6144);
    size_t FE1  = take(1048576);      // (64,128,128) BN'd SA1 features
    size_t GR3  = take(530432);
    size_t H3A  = take(524288);
    size_t H3B  = take(524288);
    size_t H3C  = take(1048576);
    size_t X3   = take(32768);
    size_t Y1   = take(65536);
    size_t Y2   = take(65536);
    size_t P1X  = take(1048576);
    size_t P1N  = take(1048576);
    size_t WT1H = take(10240);
    size_t WT1L = take(10240);
    size_t WT2H = take(8192);
    size_t WT2L = take(8192);
    size_t WT3H = take(16384);
    size_t WT3L = take(16384);
    size_t WA1H = take(1024);
    size_t WA1L = take(1024);
    size_t WB1H = take(2048);
    size_t WB1L = take(2048);
    size_t WC1H = take(4096);
    size_t WC1L = take(4096);
    size_t Z0   = o;
    size_t STT  = take(11 * 2048);
    size_t P2X  = take(524288);
    size_t Z1   = o;
    size_t P2N  = take(524288);
    size_t Z2   = o;
    size_t PSB  = take(2097152);
    size_t PQB  = take(2097152);
    size_t YB   = take(33554432);

    #define Fp(x) ((float*)(ws + (x)))
    #define Ip(x) ((int*)(ws + (x)))
    #define Up(x) ((unsigned*)(ws + (x)))
    #define Hp(x) ((unsigned short*)(ws + (x)))
    auto st = [&](int slot) { return Fp(STT + (size_t)slot * 2048 * 4); };

    hipMemsetAsync(ws + Z0, 0, Z1 - Z0, stream);
    hipMemsetAsync(ws + Z1, 0xFF, Z2 - Z1, stream);

    build_xyz_kernel<<<320, 256, 0, stream>>>(pc, gpc, Fp(XYZ));
    prep_w_kernel<<<328, 256, 0, stream>>>(w2a, w2b, w2c, w1a, w1b, w1c,
        Hp(WT1H), Hp(WT1L), Hp(WT2H), Hp(WT2L), Hp(WT3H), Hp(WT3L),
        Hp(WA1H), Hp(WA1L), Hp(WB1H), Hp(WB1L), Hp(WC1H), Hp(WC1L));

    // ---- SA1 ----
    fps_wave_kernel<20><<<64, 64, 0, stream>>>(Fp(XYZ), 1280, 128, Ip(CID1));
    ball_query_kernel<<<dim3(64, 32), 256, 0, stream>>>(Fp(XYZ), Ip(CID1), 1280, 128, 64,
                                                        (float)(0.02 * 0.02), Ip(NID1), Fp(NX1));
    sa1_s_kernel<<<8192, 256, 0, stream>>>(Fp(XYZ), Ip(NID1), Fp(NX1),
        Hp(WA1H), Hp(WA1L), Fp(PSB), Fp(PQB));
    reduce_stats_kernel<<<64, 256, 0, stream>>>(Fp(PSB), Fp(PQB), 8192, 64,
        st(0), st(0) + 1024);
    sa1_ab_kernel<<<8192, 256, 0, stream>>>(Fp(XYZ), Ip(NID1), Fp(NX1),
        Hp(WA1H), Hp(WA1L), Hp(WB1H), Hp(WB1L),
        st(0), st(0) + 1024, g1a, b1a, Fp(PSB), Fp(PQB), Fp(YB));
    reduce_stats_kernel<<<64, 256, 0, stream>>>(Fp(PSB), Fp(PQB), 8192, 64,
        st(1), st(1) + 1024);
    sa1_c_kernel<<<4096, 256, 0, stream>>>(Fp(YB), Hp(WC1H), Hp(WC1L),
        st(1), st(1) + 1024, g1b, b1b, Fp(PSB), Fp(PQB), Fp(P1X), Fp(P1N));
    reduce_stats_kernel<<<128, 256, 0, stream>>>(Fp(PSB), Fp(PQB), 4096, 128,
        st(2), st(2) + 1024);
    bnpool_fin_kernel<<<4096, 256, 0, stream>>>(Fp(P1X), Fp(P1N), st(2), st(2) + 1024,
                                                g1c, b1c, 1.f / 524288.f, Fp(FE1), 1048576, 127);

    // ---- SA2 ----
    fps_wave_kernel<2><<<64, 64, 0, stream>>>(Fp(NX1), 128, 32, Ip(CID2));
    ball_query_kernel<<<dim3(64, 8), 256, 0, stream>>>(Fp(NX1), Ip(CID2), 128, 32, 128,
                                                       (float)(0.04 * 0.04), Ip(NID2), Fp(NX2));
    sa2_a_kernel<<<4096, 256, 0, stream>>>(Fp(NX1), Ip(NID2), Fp(NX2), Fp(FE1),
        Hp(WT1H), Hp(WT1L), Fp(PSB), Fp(PQB), Fp(YB));
    reduce_stats_kernel<<<128, 256, 0, stream>>>(Fp(PSB), Fp(PQB), 4096, 128,
        st(3), st(3) + 1024);
    sa2_b_kernel<<<4096, 256, 0, stream>>>(Fp(YB), Hp(WT2H), Hp(WT2L),
        st(3), st(3) + 1024, g2a, b2a, Fp(PSB), Fp(PQB));
    reduce_stats_kernel<<<128, 256, 0, stream>>>(Fp(PSB), Fp(PQB), 4096, 128,
        st(4), st(4) + 1024);
    sa2_c_kernel<<<4096, 256, 0, stream>>>(Fp(YB), Hp(WT3H), Hp(WT3L),
        st(4), st(4) + 1024, g2b, b2b, Fp(PSB), Fp(PQB), Up(P2X), Up(P2N));
    reduce_stats_kernel<<<256, 256, 0, stream>>>(Fp(PSB), Fp(PQB), 4096, 256,
        st(5), st(5) + 1024);

    // ---- SA3 ----
    grouped3_prep_kernel<<<2048, 256, 0, stream>>>(Fp(NX2), Up(P2X), Up(P2N),
        st(5), st(5) + 1024, g2c, b2c, 1.f / 262144.f, Fp(GR3));
    gemm_bn_kernel<<<dim3(32, 4), 256, 0, stream>>>(Fp(GR3), w3a, nullptr, Fp(H3A),
        nullptr, nullptr, nullptr, nullptr, 0.f, st(6), st(6) + 1024, 2048, 259, 256);
    gemm_bn_kernel<<<dim3(32, 4), 256, 0, stream>>>(Fp(H3A), w3b, nullptr, Fp(H3B),
        st(6), st(6) + 1024, g3a, b3a, 1.f / 2048.f, st(7), st(7) + 1024, 2048, 256, 256);
    gemm_bn_kernel<<<dim3(32, 8), 256, 0, stream>>>(Fp(H3B), w3c, nullptr, Fp(H3C),
        st(7), st(7) + 1024, g3b, b3b, 1.f / 2048.f, st(8), st(8) + 1024, 2048, 256, 512);
    pool3_kernel<<<128, 256, 0, stream>>>(Fp(H3C), st(8), st(8) + 1024, g3c, b3c, Fp(X3));

    // ---- FC head (split-K) ----
    fc_gemm_kernel<<<dim3(16, 8), 256, 0, stream>>>(Fp(X3), fw1,
        nullptr, nullptr, nullptr, nullptr, 0.f, Fp(PSB), 512, 1024);
    fc_fin_kernel<<<256, 256, 0, stream>>>(Fp(PSB), fb1, 1024, 8, Fp(Y1));
    col_stats_kernel<<<4, 256, 0, stream>>>(Fp(Y1), 64, 1024, st(9), st(9) + 1024);
    fc_gemm_kernel<<<dim3(16, 8), 256, 0, stream>>>(Fp(Y1), fw2,
        st(9), st(9) + 1024, fg1, fbb1, 1.f / 64.f, Fp(PSB), 1024, 1024);
    fc_fin_kernel<<<256, 256, 0, stream>>>(Fp(PSB), fb2, 1024, 8, Fp(Y2));
    col_stats_kernel<<<4, 256, 0, stream>>>(Fp(Y2), 64, 1024, st(10), st(10) + 1024);
    head_kernel<<<64, 256, 0, stream>>>(Fp(Y2), st(10), st(10) + 1024, fg2, fbb2, hw, hb, out);

    #undef Fp
    #undef Ip
    #undef Up
    #undef Hp
}